// Round 14
// baseline (492.031 us; speedup 1.0000x reference)
//
#include <hip/hip_runtime.h>
#include <hip/hip_bf16.h>

#define G_DIM 64
#define F_DIM 128
#define C_DIM 4

typedef __bf16 bf16x8 __attribute__((ext_vector_type(8)));
typedef float  f32x4  __attribute__((ext_vector_type(4)));

__device__ inline unsigned short f2bf(float f) {
    __bf16 h = (__bf16)f;                 // HW v_cvt (RTNE) on gfx950
    union { __bf16 b; unsigned short u; } v; v.b = h;
    return v.u;
}

__device__ inline float ssp(float x) {
    float t = __expf(-fabsf(x));
    return fmaxf(x, 0.f) + __logf(1.f + t) - 0.69314718055994531f;
}

// Weights -> bf16 transposed: w1t[c][n][k] = W1[c][k][n]; w2t[c][n][k] = W2[c][k][n]
__global__ void k_convert(const float* __restrict__ W1, const float* __restrict__ W2,
                          unsigned short* __restrict__ w1t, unsigned short* __restrict__ w2t) {
    int i = blockIdx.x * 256 + threadIdx.x;
    if (i < C_DIM * F_DIM * G_DIM) {
        int k = i % G_DIM, n = (i / G_DIM) % F_DIM, c = i / (G_DIM * F_DIM);
        w1t[i] = f2bf(W1[(c * G_DIM + k) * F_DIM + n]);
    }
    if (i < C_DIM * F_DIM * F_DIM) {
        int k = i % F_DIM, n = (i / F_DIM) % F_DIM, c = i / (F_DIM * F_DIM);
        w2t[i] = f2bf(W2[(c * F_DIM + k) * F_DIM + n]);
    }
}

// Sort-free fused MLP: one block = 64 CONSECUTIVE edges (streaming I/O).
// Static #pragma-unroll loop over the 4 color experts; per color:
// GEMM1 -> masked ssp->H (rows of that color) -> GEMM2 -> masked nt stores.
// Stale/garbage H rows feed only discarded output rows (MFMA rows independent).
// 4 waves; wave w owns output cols [w*32, w*32+32); weights register-resident
// per color iteration (static addresses -> compiler keeps them in VGPRs).
// LDS = A(9216) + H(17408) = 26624 B -> 6 blocks/CU.
__global__ __launch_bounds__(256, 6) void mlp_main(
    const float* __restrict__ ea, const int* __restrict__ colors,
    const float* __restrict__ b1, const float* __restrict__ b2,
    const unsigned short* __restrict__ w1t, const unsigned short* __restrict__ w2t,
    float* __restrict__ out, int E) {
    __shared__ __align__(16) unsigned short A[64][72];   // 144B stride (clean)
    __shared__ __align__(16) unsigned short H[64][136];  // 272B stride (clean)

    int r0 = blockIdx.x * 64;
    int tid = threadIdx.x, w = tid >> 6, lane = tid & 63;
    int l15 = lane & 15, l4 = lane >> 4;

    // per-wave row colors (natural order; -1 for OOB rows)
    int rc = (r0 + lane < E) ? colors[r0 + lane] : -1;

    // ---- stage A: streaming read, natural-order LDS write ----
    {
        int r = w * 16 + (lane >> 2), q = lane & 3;
        unsigned short tmp[16];
        if (r0 + r < E) {
            const float4* src = (const float4*)(ea + (size_t)(r0 + r) * G_DIM + q * 16);
#pragma unroll
            for (int i = 0; i < 4; ++i) {
                float4 v = src[i];
                tmp[i * 4 + 0] = f2bf(v.x); tmp[i * 4 + 1] = f2bf(v.y);
                tmp[i * 4 + 2] = f2bf(v.z); tmp[i * 4 + 3] = f2bf(v.w);
            }
        } else {
#pragma unroll
            for (int i = 0; i < 16; ++i) tmp[i] = 0;
        }
        *(uint4*)&A[r][q * 16]     = *(uint4*)&tmp[0];
        *(uint4*)&A[r][q * 16 + 8] = *(uint4*)&tmp[8];
    }
    __syncthreads();                                   // B0: A staged

#pragma unroll
    for (int c = 0; c < C_DIM; ++c) {
        // ---- GEMM1 weights for color c (static, register-resident) ----
        bf16x8 fB1[2][2]; float bias1[2];
#pragma unroll
        for (int nt = 0; nt < 2; ++nt) {
            int n = w * 32 + nt * 16 + l15;
            bias1[nt] = b1[c * F_DIM + n];
#pragma unroll
            for (int ks = 0; ks < 2; ++ks)
                fB1[nt][ks] = *(const bf16x8*)(w1t + ((size_t)(c * F_DIM + n) * G_DIM + ks * 32 + l4 * 8));
        }

        // ---- GEMM1: h = A @ W1_c ----
        f32x4 acc[4][2];
#pragma unroll
        for (int mt = 0; mt < 4; ++mt)
#pragma unroll
            for (int nt = 0; nt < 2; ++nt) acc[mt][nt] = (f32x4){0.f, 0.f, 0.f, 0.f};
#pragma unroll
        for (int ks = 0; ks < 2; ++ks) {
#pragma unroll
            for (int mt = 0; mt < 4; ++mt) {
                bf16x8 a = *(const bf16x8*)&A[mt * 16 + l15][ks * 32 + l4 * 8];
                acc[mt][0] = __builtin_amdgcn_mfma_f32_16x16x32_bf16(a, fB1[0][ks], acc[mt][0], 0, 0, 0);
                acc[mt][1] = __builtin_amdgcn_mfma_f32_16x16x32_bf16(a, fB1[1][ks], acc[mt][1], 0, 0, 0);
            }
        }

        // ---- masked bias + ssp -> H (only rows of color c) ----
#pragma unroll
        for (int mt = 0; mt < 4; ++mt)
#pragma unroll
            for (int r = 0; r < 4; ++r) {
                int row = mt * 16 + l4 * 4 + r;
                if (__shfl(rc, row, 64) == c) {
#pragma unroll
                    for (int nt = 0; nt < 2; ++nt) {
                        float v = acc[mt][nt][r] + bias1[nt];
                        H[row][w * 32 + nt * 16 + l15] = f2bf(ssp(v));
                    }
                }
            }

        // ---- GEMM2 weights for color c (overlap barrier wait) ----
        bf16x8 fB2[2][4]; float bias2[2];
#pragma unroll
        for (int nt = 0; nt < 2; ++nt) {
            int n = w * 32 + nt * 16 + l15;
            bias2[nt] = b2[c * F_DIM + n];
#pragma unroll
            for (int ks = 0; ks < 4; ++ks)
                fB2[nt][ks] = *(const bf16x8*)(w2t + ((size_t)(c * F_DIM + n) * F_DIM + ks * 32 + l4 * 8));
        }
        __syncthreads();                               // H(c) rows ready

        // ---- GEMM2: y = H @ W2_c ----
#pragma unroll
        for (int mt = 0; mt < 4; ++mt)
#pragma unroll
            for (int nt = 0; nt < 2; ++nt) acc[mt][nt] = (f32x4){0.f, 0.f, 0.f, 0.f};
#pragma unroll
        for (int ks = 0; ks < 4; ++ks) {
#pragma unroll
            for (int mt = 0; mt < 4; ++mt) {
                bf16x8 a = *(const bf16x8*)&H[mt * 16 + l15][ks * 32 + l4 * 8];
                acc[mt][0] = __builtin_amdgcn_mfma_f32_16x16x32_bf16(a, fB2[0][ks], acc[mt][0], 0, 0, 0);
                acc[mt][1] = __builtin_amdgcn_mfma_f32_16x16x32_bf16(a, fB2[1][ks], acc[mt][1], 0, 0, 0);
            }
        }

        // ---- masked bias + nt stores (only rows of color c; streaming window) ----
#pragma unroll
        for (int mt = 0; mt < 4; ++mt) {
#pragma unroll
            for (int r = 0; r < 4; ++r) {
                int row = mt * 16 + l4 * 4 + r;
                if (__shfl(rc, row, 64) == c) {
                    float* p = out + (size_t)(r0 + row) * F_DIM + w * 32 + l15;
                    __builtin_nontemporal_store(acc[mt][0][r] + bias2[0], p);
                    __builtin_nontemporal_store(acc[mt][1][r] + bias2[1], p + 16);
                }
            }
        }
        __syncthreads();                               // H reads done; next c may overwrite
    }
}

// Correct-but-slow fallback if ws is too small (insurance only).
__global__ void fallback(const float* __restrict__ ea, const int* __restrict__ colors,
                         const float* __restrict__ W1, const float* __restrict__ b1,
                         const float* __restrict__ W2, const float* __restrict__ b2,
                         float* __restrict__ out, int E) {
    __shared__ float sh[4][F_DIM + G_DIM];
    int w = threadIdx.x >> 6, lane = threadIdx.x & 63;
    int e = blockIdx.x * 4 + w;
    bool valid = (e < E);
    int ec = valid ? e : 0;
    int c = colors[ec];
    float* hv = sh[w];
    float* av = sh[w] + F_DIM;
    av[lane] = ea[(size_t)ec * G_DIM + lane];
    __syncthreads();
    for (int f = lane; f < F_DIM; f += 64) {
        float s = b1[c * F_DIM + f];
        for (int g = 0; g < G_DIM; ++g) s += av[g] * W1[(c * G_DIM + g) * F_DIM + f];
        hv[f] = ssp(s);
    }
    __syncthreads();
    for (int f = lane; f < F_DIM; f += 64) {
        float s = b2[c * F_DIM + f];
        for (int k = 0; k < F_DIM; ++k) s += hv[k] * W2[(c * F_DIM + k) * F_DIM + f];
        if (valid) out[(size_t)e * F_DIM + f] = s;
    }
}

extern "C" void kernel_launch(void* const* d_in, const int* in_sizes, int n_in,
                              void* d_out, int out_size, void* d_ws, size_t ws_size,
                              hipStream_t stream) {
    const float* ea     = (const float*)d_in[0];
    const int*   colors = (const int*)d_in[1];
    const float* W1     = (const float*)d_in[2];
    const float* b1     = (const float*)d_in[3];
    const float* W2     = (const float*)d_in[4];
    const float* b2     = (const float*)d_in[5];
    float* out = (float*)d_out;
    int E = in_sizes[1];

    size_t need = (size_t)(C_DIM * F_DIM * G_DIM + C_DIM * F_DIM * F_DIM) * 2;
    if (ws_size < need) {
        int blocks = (E + 3) / 4;
        fallback<<<blocks, 256, 0, stream>>>(ea, colors, W1, b1, W2, b2, out, E);
        return;
    }

    unsigned short* w1t = (unsigned short*)d_ws;
    unsigned short* w2t = w1t + C_DIM * F_DIM * G_DIM;

    k_convert<<<256, 256, 0, stream>>>(W1, W2, w1t, w2t);
    int g = (E + 63) / 64;
    mlp_main<<<g, 256, 0, stream>>>(ea, colors, b1, b2, w1t, w2t, out, E);
}

// Round 15
// 91.521 us; speedup vs baseline: 5.3761x; 5.3761x over previous
//
#include <hip/hip_runtime.h>
#include <hip/hip_bf16.h>

#define G_DIM 64
#define F_DIM 128
#define C_DIM 4
#define NB    512   // histogram/scatter blocks (multiple of 64)

// meta layout in ws (uint32 slots)
#define META_COUNTS 0   // 4
#define META_BASES  4   // 5 (exclusive prefix, [4]=E)
#define META_TSTART 9   // 5 (tile-base prefix, [4]=total tiles)
#define BH_OFF      32            // block histograms: NB*4 uint32
#define IDX_OFF     (32 + NB*C_DIM)

typedef __bf16 bf16x8 __attribute__((ext_vector_type(8)));
typedef float  f32x4  __attribute__((ext_vector_type(4)));

__device__ inline unsigned short f2bf(float f) {
    __bf16 h = (__bf16)f;                 // HW v_cvt (RTNE) on gfx950
    union { __bf16 b; unsigned short u; } v; v.b = h;
    return v.u;
}

__device__ inline float ssp(float x) {
    float t = __expf(-fabsf(x));
    return fmaxf(x, 0.f) + __logf(1.f + t) - 0.69314718055994531f;
}

// ---- fused: blocks [0,NB) histogram; blocks [NB,NB+256) weight convert ----
__global__ void k_prep1(const int* __restrict__ colors, int E, int CH,
                        unsigned* __restrict__ bh,
                        const float* __restrict__ W1, const float* __restrict__ W2,
                        unsigned short* __restrict__ w1t, unsigned short* __restrict__ w2t) {
    int tid = threadIdx.x;
    if (blockIdx.x < NB) {
        __shared__ unsigned h[C_DIM];
        if (tid < C_DIM) h[tid] = 0;
        __syncthreads();
        int lo = blockIdx.x * CH, hi = lo + CH; if (hi > E) hi = E;
        int lane = tid & 63;
        for (int i0 = lo; i0 < hi; i0 += 256) {
            int i = i0 + tid;
            int c = (i < hi) ? colors[i] : -1;
#pragma unroll
            for (int cc = 0; cc < C_DIM; ++cc) {
                unsigned long long m = __ballot(c == cc);
                if (lane == 0 && m) atomicAdd(&h[cc], (unsigned)__popcll(m));
            }
        }
        __syncthreads();
        if (tid < C_DIM) bh[blockIdx.x * C_DIM + tid] = h[tid];
    } else {
        int i = (blockIdx.x - NB) * 256 + tid;
        if (i < C_DIM * F_DIM * G_DIM) {
            int k = i % G_DIM, n = (i / G_DIM) % F_DIM, c = i / (G_DIM * F_DIM);
            w1t[i] = f2bf(W1[(c * G_DIM + k) * F_DIM + n]);
        }
        if (i < C_DIM * F_DIM * F_DIM) {
            int k = i % F_DIM, n = (i / F_DIM) % F_DIM, c = i / (F_DIM * F_DIM);
            w2t[i] = f2bf(W2[(c * F_DIM + k) * F_DIM + n]);
        }
    }
}

// ---- fused: redundant scan (per block) + scatter; block 0 writes meta ----
__global__ void k_prep2(const int* __restrict__ colors, int E, int CH,
                        const unsigned* __restrict__ bh, unsigned* __restrict__ meta,
                        int* __restrict__ idx) {
    __shared__ unsigned cur[C_DIM], tmpb[C_DIM], tot[C_DIM];
    int tid = threadIdx.x, w = tid >> 6, lane = tid & 63;

    unsigned run = 0;
    for (int b0 = 0; b0 < NB; b0 += 64) {
        int b = b0 + lane;
        unsigned v = bh[b * C_DIM + w];
        unsigned s = v;
#pragma unroll
        for (int d = 1; d < 64; d <<= 1) {
            unsigned t = __shfl_up(s, d, 64);
            if (lane >= d) s += t;
        }
        if (b == (int)blockIdx.x) tmpb[w] = run + s - v;
        run += __shfl(s, 63, 64);
    }
    if (lane == 0) tot[w] = run;
    __syncthreads();
    if (blockIdx.x == 0 && tid == 0) {
        unsigned bsum = 0, tsum = 0;
#pragma unroll
        for (int c = 0; c < C_DIM; ++c) {
            meta[META_BASES + c] = bsum;
            meta[META_COUNTS + c] = tot[c];
            meta[META_TSTART + c] = tsum;
            bsum += tot[c];
            tsum += (tot[c] + 63) >> 6;
        }
        meta[META_BASES + C_DIM] = bsum;
        meta[META_TSTART + C_DIM] = tsum;
    }
    if (lane == 0) {
        unsigned cb = 0;
        for (int c = 0; c < w; ++c) cb += tot[c];
        cur[w] = tmpb[w] + cb;
    }
    __syncthreads();

    int lo = blockIdx.x * CH, hi = lo + CH; if (hi > E) hi = E;
    for (int i0 = lo; i0 < hi; i0 += 256) {
        int i = i0 + tid;
        int c = (i < hi) ? colors[i] : -1;
#pragma unroll
        for (int cc = 0; cc < C_DIM; ++cc) {
            unsigned long long m = __ballot(c == cc);
            if (!m) continue;
            int leader = __ffsll(m) - 1;
            unsigned base = 0;
            if (lane == leader) base = atomicAdd(&cur[cc], (unsigned)__popcll(m));
            base = __shfl(base, leader, 64);
            if (c == cc) {
                unsigned off = __popcll(m & ((1ull << lane) - 1ull));
                idx[base + off] = i;
            }
        }
    }
}

// Main fused MLP (round-7 proven structure, best measured 91.6us):
// one block = 64 same-color edges (sorted via idx); 4 waves, wave w owns cols
// [w*32,w*32+32); weights register-resident; nt stores (load-bearing, r9).
// LDS = A(9216) + H(17408) = 26624 B -> 6 blocks/CU. Two barriers total.
__global__ __launch_bounds__(256, 6) void mlp_main(
    const float* __restrict__ ea, const float* __restrict__ b1,
    const float* __restrict__ b2, const unsigned short* __restrict__ w1t,
    const unsigned short* __restrict__ w2t, const unsigned* __restrict__ meta,
    const int* __restrict__ idx, float* __restrict__ out) {
    __shared__ __align__(16) unsigned short A[64][72];   // 144B stride (clean)
    __shared__ __align__(16) unsigned short H[64][136];  // 272B stride (clean)

    unsigned b = blockIdx.x;
    if (b >= meta[META_TSTART + C_DIM]) return;
    int c = 0;
    if (b >= meta[META_TSTART + 1]) c = 1;
    if (b >= meta[META_TSTART + 2]) c = 2;
    if (b >= meta[META_TSTART + 3]) c = 3;
    int t = (int)(b - meta[META_TSTART + c]);
    int segBase = (int)meta[META_BASES + c];
    int segCnt  = (int)meta[META_COUNTS + c];
    int row0 = t * 64;
    int nrows = segCnt - row0; if (nrows > 64) nrows = 64;

    int tid = threadIdx.x, w = tid >> 6, lane = tid & 63;
    int l15 = lane & 15, l4 = lane >> 4;

    // all 64 edge ids per wave (256B coalesced load, redundant across waves)
    int e_all = (lane < nrows) ? idx[segBase + row0 + lane] : -1;

    // ---- stage A (gather edge rows, f32 -> bf16) ----
    {
        int e = __shfl(e_all, w * 16 + (lane >> 2), 64);
        int r = w * 16 + (lane >> 2), q = lane & 3;
        unsigned short tmp[16];
        if (e >= 0) {
            const float4* src = (const float4*)(ea + (size_t)e * G_DIM + q * 16);
#pragma unroll
            for (int i = 0; i < 4; ++i) {
                float4 v = src[i];
                tmp[i * 4 + 0] = f2bf(v.x); tmp[i * 4 + 1] = f2bf(v.y);
                tmp[i * 4 + 2] = f2bf(v.z); tmp[i * 4 + 3] = f2bf(v.w);
            }
        } else {
#pragma unroll
            for (int i = 0; i < 16; ++i) tmp[i] = 0;
        }
        *(uint4*)&A[r][q * 16]     = *(uint4*)&tmp[0];
        *(uint4*)&A[r][q * 16 + 8] = *(uint4*)&tmp[8];
    }

    // ---- GEMM1 weights (register-resident before MFMA) ----
    bf16x8 fB1[2][2]; float bias1[2];
#pragma unroll
    for (int nt = 0; nt < 2; ++nt) {
        int n = w * 32 + nt * 16 + l15;
        bias1[nt] = b1[c * F_DIM + n];
#pragma unroll
        for (int ks = 0; ks < 2; ++ks)
            fB1[nt][ks] = *(const bf16x8*)(w1t + ((size_t)(c * F_DIM + n) * G_DIM + ks * 32 + l4 * 8));
    }
    __syncthreads();                                   // B1: A staged

    // ---- GEMM1: h = A @ W1 ----
    f32x4 acc[4][2];
#pragma unroll
    for (int mt = 0; mt < 4; ++mt)
#pragma unroll
        for (int nt = 0; nt < 2; ++nt) acc[mt][nt] = (f32x4){0.f, 0.f, 0.f, 0.f};
#pragma unroll
    for (int ks = 0; ks < 2; ++ks) {
#pragma unroll
        for (int mt = 0; mt < 4; ++mt) {
            bf16x8 a = *(const bf16x8*)&A[mt * 16 + l15][ks * 32 + l4 * 8];
            acc[mt][0] = __builtin_amdgcn_mfma_f32_16x16x32_bf16(a, fB1[0][ks], acc[mt][0], 0, 0, 0);
            acc[mt][1] = __builtin_amdgcn_mfma_f32_16x16x32_bf16(a, fB1[1][ks], acc[mt][1], 0, 0, 0);
        }
    }

    // ---- bias + shifted-softplus -> H (bf16) ----
#pragma unroll
    for (int mt = 0; mt < 4; ++mt)
#pragma unroll
        for (int nt = 0; nt < 2; ++nt)
#pragma unroll
            for (int r = 0; r < 4; ++r) {
                float v = acc[mt][nt][r] + bias1[nt];
                H[mt * 16 + l4 * 4 + r][w * 32 + nt * 16 + l15] = f2bf(ssp(v));
            }

    // ---- GEMM2 weights (register-resident; loads overlap barrier wait) ----
    bf16x8 fB2[2][4]; float bias2[2];
#pragma unroll
    for (int nt = 0; nt < 2; ++nt) {
        int n = w * 32 + nt * 16 + l15;
        bias2[nt] = b2[c * F_DIM + n];
#pragma unroll
        for (int ks = 0; ks < 4; ++ks)
            fB2[nt][ks] = *(const bf16x8*)(w2t + ((size_t)(c * F_DIM + n) * F_DIM + ks * 32 + l4 * 8));
    }
    __syncthreads();                                   // B2: H ready

    // ---- GEMM2: y = H @ W2 ----
#pragma unroll
    for (int mt = 0; mt < 4; ++mt)
#pragma unroll
        for (int nt = 0; nt < 2; ++nt) acc[mt][nt] = (f32x4){0.f, 0.f, 0.f, 0.f};
#pragma unroll
    for (int ks = 0; ks < 4; ++ks) {
#pragma unroll
        for (int mt = 0; mt < 4; ++mt) {
            bf16x8 a = *(const bf16x8*)&H[mt * 16 + l15][ks * 32 + l4 * 8];
            acc[mt][0] = __builtin_amdgcn_mfma_f32_16x16x32_bf16(a, fB2[0][ks], acc[mt][0], 0, 0, 0);
            acc[mt][1] = __builtin_amdgcn_mfma_f32_16x16x32_bf16(a, fB2[1][ks], acc[mt][1], 0, 0, 0);
        }
    }

    // ---- bias + direct non-temporal stores ----
#pragma unroll
    for (int mt = 0; mt < 4; ++mt) {
#pragma unroll
        for (int r = 0; r < 4; ++r) {
            int e = __shfl(e_all, mt * 16 + l4 * 4 + r, 64);
            if (e >= 0) {
                float* p = out + (size_t)e * F_DIM + w * 32 + l15;
                __builtin_nontemporal_store(acc[mt][0][r] + bias2[0], p);
                __builtin_nontemporal_store(acc[mt][1][r] + bias2[1], p + 16);
            }
        }
    }
}

// Correct-but-slow fallback if ws is too small (insurance only).
__global__ void fallback(const float* __restrict__ ea, const int* __restrict__ colors,
                         const float* __restrict__ W1, const float* __restrict__ b1,
                         const float* __restrict__ W2, const float* __restrict__ b2,
                         float* __restrict__ out, int E) {
    __shared__ float sh[4][F_DIM + G_DIM];
    int w = threadIdx.x >> 6, lane = threadIdx.x & 63;
    int e = blockIdx.x * 4 + w;
    bool valid = (e < E);
    int ec = valid ? e : 0;
    int c = colors[ec];
    float* hv = sh[w];
    float* av = sh[w] + F_DIM;
    av[lane] = ea[(size_t)ec * G_DIM + lane];
    __syncthreads();
    for (int f = lane; f < F_DIM; f += 64) {
        float s = b1[c * F_DIM + f];
        for (int g = 0; g < G_DIM; ++g) s += av[g] * W1[(c * G_DIM + g) * F_DIM + f];
        hv[f] = ssp(s);
    }
    __syncthreads();
    for (int f = lane; f < F_DIM; f += 64) {
        float s = b2[c * F_DIM + f];
        for (int k = 0; k < F_DIM; ++k) s += hv[k] * W2[(c * F_DIM + k) * F_DIM + f];
        if (valid) out[(size_t)e * F_DIM + f] = s;
    }
}

extern "C" void kernel_launch(void* const* d_in, const int* in_sizes, int n_in,
                              void* d_out, int out_size, void* d_ws, size_t ws_size,
                              hipStream_t stream) {
    const float* ea     = (const float*)d_in[0];
    const int*   colors = (const int*)d_in[1];
    const float* W1     = (const float*)d_in[2];
    const float* b1     = (const float*)d_in[3];
    const float* W2     = (const float*)d_in[4];
    const float* b2     = (const float*)d_in[5];
    float* out = (float*)d_out;
    int E = in_sizes[1];

    size_t need = (size_t)(IDX_OFF + E) * 4 +
                  (size_t)(C_DIM * F_DIM * G_DIM + C_DIM * F_DIM * F_DIM) * 2;
    if (ws_size < need) {
        int blocks = (E + 3) / 4;
        fallback<<<blocks, 256, 0, stream>>>(ea, colors, W1, b1, W2, b2, out, E);
        return;
    }

    unsigned* meta = (unsigned*)d_ws;
    unsigned* bh   = (unsigned*)d_ws + BH_OFF;
    int* idx = (int*)d_ws + IDX_OFF;
    unsigned short* w1t = (unsigned short*)((char*)d_ws + (size_t)(IDX_OFF + E) * 4);
    unsigned short* w2t = w1t + C_DIM * F_DIM * G_DIM;

    int CH = (E + NB - 1) / NB;
    k_prep1<<<NB + 256, 256, 0, stream>>>(colors, E, CH, bh, W1, W2, w1t, w2t);
    k_prep2<<<NB, 256, 0, stream>>>(colors, E, CH, bh, meta, idx);
    int g = (E + 63) / 64 + C_DIM;
    mlp_main<<<g, 256, 0, stream>>>(ea, b1, b2, w1t, w2t, meta, idx, out);
}